// Round 2
// baseline (337.421 us; speedup 1.0000x reference)
//
#include <hip/hip_runtime.h>

typedef unsigned short u16;
typedef __attribute__((ext_vector_type(8))) short short8;
typedef __attribute__((ext_vector_type(4))) float f32x4;

__device__ __forceinline__ float bf2f(u16 h) {
    union { unsigned u; float f; } v; v.u = ((unsigned)h) << 16; return v.f;
}
__device__ __forceinline__ u16 f2bf(float f) {
    union { float f; unsigned u; } v; v.f = f;
    unsigned u = v.u;
    u += 0x7FFFu + ((u >> 16) & 1u);   // round-to-nearest-even
    return (u16)(u >> 16);
}

// ---- dtype detection ------------------------------------------------------
// flag=1 iff x buffer is float32: even-indexed u16 words are float32 low
// mantissa halves -> uniformly random exponent fields. bf16 N(0,1) data has
// exponents clustered in ~[106,130].
__global__ void k_detect(const u16* __restrict__ x, int* __restrict__ flag) {
    __shared__ int c_s;
    if (threadIdx.x == 0) c_s = 0;
    __syncthreads();
    int c = 0;
    for (int i = threadIdx.x; i < 2048; i += blockDim.x) {
        int e = (x[2 * i] >> 7) & 0xFF;
        c += (e >= 160 || e <= 80) ? 1 : 0;
    }
    atomicAdd(&c_s, c);
    __syncthreads();
    if (threadIdx.x == 0) *flag = (c_s > 64) ? 1 : 0;
}

__global__ void k_convert(const void* __restrict__ in, u16* __restrict__ out,
                          int n, const int* __restrict__ flag) {
    int i = blockIdx.x * blockDim.x + threadIdx.x;
    if (i >= n) return;
    if (*flag) out[i] = f2bf(((const float*)in)[i]);
    else       out[i] = ((const u16*)in)[i];
}

// ---- CSR build ------------------------------------------------------------

__global__ void k_degree(const int* __restrict__ dst, int* __restrict__ cnt, int E) {
    int e = blockIdx.x * blockDim.x + threadIdx.x;
    if (e < E) atomicAdd(&cnt[dst[e]], 1);
}

// exclusive scan within each 256-block, written straight into rowp; block sums out
__global__ void k_scan_blocks(const int* __restrict__ cnt, int* __restrict__ rowp,
                              int* __restrict__ sums, int n) {
    __shared__ int s[256];
    int t = threadIdx.x;
    int i = blockIdx.x * 256 + t;
    int v = (i < n) ? cnt[i] : 0;
    s[t] = v;
    __syncthreads();
    for (int off = 1; off < 256; off <<= 1) {
        int add = (t >= off) ? s[t - off] : 0;
        __syncthreads();
        s[t] += add;
        __syncthreads();
    }
    if (i < n) rowp[i] = s[t] - v;
    if (t == 255) sums[blockIdx.x] = s[255];
}

__global__ void k_scan_top(int* __restrict__ sums, int nb) {
    __shared__ int s[256];
    int t = threadIdx.x;
    int v = (t < nb) ? sums[t] : 0;
    s[t] = v;
    __syncthreads();
    for (int off = 1; off < 256; off <<= 1) {
        int add = (t >= off) ? s[t - off] : 0;
        __syncthreads();
        s[t] += add;
        __syncthreads();
    }
    sums[t] = s[t] - v;
}

__global__ void k_finalize(int* __restrict__ rowp, const int* __restrict__ sums,
                           const int* __restrict__ cnt, float* __restrict__ dinv,
                           int n, int E) {
    int i = blockIdx.x * 256 + threadIdx.x;
    if (i < n) {
        rowp[i] += sums[i >> 8];
        dinv[i] = rsqrtf((float)cnt[i] + 1.0f);   // deg includes self-loop
    }
    if (i == 0) rowp[n] = E;
}

__global__ void k_fill(const int* __restrict__ src, const int* __restrict__ dst,
                       const int* __restrict__ rowp, int* __restrict__ fill,
                       int* __restrict__ col, int E) {
    int e = blockIdx.x * blockDim.x + threadIdx.x;
    if (e < E) {
        int d = dst[e];
        int p = rowp[d] + atomicAdd(&fill[d], 1);
        col[p] = src[e];
    }
}

// ---- GEMM (bf16 MFMA) with fused dinv scaling: out = (A @ W) * dinv[:,None]

template <int NOUT>
__global__ void k_gemm_scale(const u16* __restrict__ A, const u16* __restrict__ W,
                             const float* __restrict__ dinv, u16* __restrict__ out, int M) {
    __shared__ u16 Wt[NOUT][136];   // 136: 16B-aligned rows, no 16-way conflicts
    int t = threadIdx.x;
    for (int idx = t; idx < NOUT * 128; idx += 256) {
        int k = idx / NOUT, n = idx % NOUT;   // W row-major [128][NOUT]
        Wt[n][k] = W[idx];
    }
    __syncthreads();
    int wave = t >> 6, lane = t & 63;
    int m0 = (blockIdx.x * 4 + wave) * 16;
    if (m0 >= M) return;
    int q = lane >> 4;       // k-quad
    int mr = lane & 15;

    const u16* arow = A + (size_t)(m0 + mr) * 128 + q * 8;
    short8 a[4];
#pragma unroll
    for (int c = 0; c < 4; c++) a[c] = *(const short8*)(arow + c * 32);

    f32x4 acc[NOUT / 16];
#pragma unroll
    for (int tl = 0; tl < NOUT / 16; tl++) acc[tl] = (f32x4){0.f, 0.f, 0.f, 0.f};

#pragma unroll
    for (int c = 0; c < 4; c++) {
#pragma unroll
        for (int tl = 0; tl < NOUT / 16; tl++) {
            short8 b = *(const short8*)(&Wt[tl * 16 + mr][c * 32 + q * 8]);
            acc[tl] = __builtin_amdgcn_mfma_f32_16x16x32_bf16(a[c], b, acc[tl], 0, 0, 0);
        }
    }

    int rbase = m0 + q * 4;   // C/D: col=lane&15, row=(lane>>4)*4+reg
#pragma unroll
    for (int tl = 0; tl < NOUT / 16; tl++) {
#pragma unroll
        for (int r = 0; r < 4; r++) {
            int row = rbase + r;
            float v = acc[tl][r] * dinv[row];
            out[(size_t)row * NOUT + tl * 16 + mr] = f2bf(v);
        }
    }
}

// ---- CSR gather aggregation: out[d] = relu(dinv[d]*(sum g[src] + g[d]) + b)

template <int F>
__global__ void k_aggregate(const u16* __restrict__ g, const int* __restrict__ rowp,
                            const int* __restrict__ col, const float* __restrict__ dinv,
                            const u16* __restrict__ bias, u16* __restrict__ outh,
                            float* __restrict__ outf, const int* __restrict__ flag,
                            int N, int E) {
    int d = blockIdx.x;
    int f = threadIdx.x;
    int beg = rowp[d], end = rowp[d + 1];
    if (beg < 0) beg = 0;
    if (end > E) end = E;
    float acc = 0.f;
    for (int e = beg; e < end; e++) {
        int s = col[e];
        s = s < 0 ? 0 : (s >= N ? N - 1 : s);   // defensive clamp
        acc += bf2f(g[(size_t)s * F + f]);
    }
    float v = dinv[d] * (acc + bf2f(g[(size_t)d * F + f])) + bf2f(bias[f]);
    v = v > 0.f ? v : 0.f;
    size_t o = (size_t)d * F + f;
    if (flag && *flag) outf[o] = v;
    else               outh[o] = f2bf(v);
}

// ---- launch ---------------------------------------------------------------

extern "C" void kernel_launch(void* const* d_in, const int* in_sizes, int n_in,
                              void* d_out, int out_size, void* d_ws, size_t ws_size,
                              hipStream_t stream) {
    const int N = in_sizes[0] / 128;
    const int E = in_sizes[1] / 2;
    const int* ei = (const int*)d_in[1];
    const int* src = ei;
    const int* dst = ei + E;

    char* p = (char*)d_ws;
    auto alloc = [&](size_t b) { char* r = p; p += (b + 255) & ~(size_t)255; return r; };
    int*   flag = (int*)alloc(256);
    int*   rowp = (int*)alloc((size_t)(N + 1) * 4);
    float* dinv = (float*)alloc((size_t)N * 4);
    int*   col  = (int*)alloc((size_t)E * 4);
    u16*   wbuf = (u16*)alloc((size_t)(128 * 128 + 128 + 128 * 64 + 64) * 2);
    char*  slotA = alloc((size_t)N * 128 * 2);   // cnt/fill/sums early; g1; g2
    char*  slotB = alloc((size_t)N * 128 * 2);   // xC early; o1 later

    // slotA overlays (dead before GEMM1 writes g1)
    int* cnt  = (int*)slotA;
    int* fill = (int*)(slotA + (size_t)N * 4);
    int* sums = (int*)(slotA + (size_t)2 * N * 4);
    u16* g1   = (u16*)slotA;
    u16* g2   = (u16*)slotA;
    // slotB overlays
    u16* xC   = (u16*)slotB;
    u16* o1   = (u16*)slotB;
    // canonical weights
    u16* W1C = wbuf;
    u16* b1C = wbuf + 128 * 128;
    u16* W2C = b1C + 128;
    u16* b2C = W2C + 128 * 64;

    // 1. dtype detect + canonicalize to bf16
    k_detect<<<1, 256, 0, stream>>>((const u16*)d_in[0], flag);
    int xel = N * 128;
    k_convert<<<(xel + 255) / 256, 256, 0, stream>>>(d_in[0], xC, xel, flag);
    k_convert<<<64, 256, 0, stream>>>(d_in[2], W1C, 128 * 128, flag);
    k_convert<<<1, 256, 0, stream>>>(d_in[3], b1C, 128, flag);
    k_convert<<<32, 256, 0, stream>>>(d_in[4], W2C, 128 * 64, flag);
    k_convert<<<1, 256, 0, stream>>>(d_in[5], b2C, 64, flag);

    // 2. CSR build
    hipMemsetAsync(slotA, 0, (size_t)2 * N * 4 + 1024, stream);  // cnt+fill+sums
    int eb = (E + 255) / 256;
    int nb = (N + 255) / 256;
    k_degree<<<eb, 256, 0, stream>>>(dst, cnt, E);
    k_scan_blocks<<<nb, 256, 0, stream>>>(cnt, rowp, sums, N);
    k_scan_top<<<1, 256, 0, stream>>>(sums, nb);
    k_finalize<<<nb, 256, 0, stream>>>(rowp, sums, cnt, dinv, N, E);
    k_fill<<<eb, 256, 0, stream>>>(src, dst, rowp, fill, col, E);

    // 3. layer 1: GEMM (xC @ W1)*dinv -> g1 (slotA), aggregate -> o1 (slotB)
    int gb = (N / 16 + 3) / 4;
    k_gemm_scale<128><<<gb, 256, 0, stream>>>(xC, W1C, dinv, g1, N);
    k_aggregate<128><<<N, 128, 0, stream>>>(g1, rowp, col, dinv, b1C,
                                            o1, nullptr, nullptr, N, E);
    // 4. layer 2: GEMM (o1 @ W2)*dinv -> g2 (slotA), aggregate -> d_out
    k_gemm_scale<64><<<gb, 256, 0, stream>>>(o1, W2C, dinv, g2, N);
    k_aggregate<64><<<N, 64, 0, stream>>>(g2, rowp, col, dinv, b2C,
                                          (u16*)d_out, (float*)d_out, flag, N, E);
}

// Round 4
// 274.555 us; speedup vs baseline: 1.2290x; 1.2290x over previous
//
#include <hip/hip_runtime.h>

typedef unsigned short u16;
typedef __attribute__((ext_vector_type(8))) short short8;
typedef __attribute__((ext_vector_type(4))) float f32x4;

__device__ __forceinline__ float bf2f(u16 h) {
    union { unsigned u; float f; } v; v.u = ((unsigned)h) << 16; return v.f;
}
__device__ __forceinline__ u16 f2bf(float f) {
    union { float f; unsigned u; } v; v.f = f;
    unsigned u = v.u;
    u += 0x7FFFu + ((u >> 16) & 1u);   // round-to-nearest-even
    return (u16)(u >> 16);
}

// ---- dtype detection ------------------------------------------------------
__global__ void k_detect(const u16* __restrict__ x, int* __restrict__ flag) {
    __shared__ int c_s;
    if (threadIdx.x == 0) c_s = 0;
    __syncthreads();
    int c = 0;
    for (int i = threadIdx.x; i < 2048; i += blockDim.x) {
        int e = (x[2 * i] >> 7) & 0xFF;
        c += (e >= 160 || e <= 80) ? 1 : 0;
    }
    atomicAdd(&c_s, c);
    __syncthreads();
    if (threadIdx.x == 0) *flag = (c_s > 64) ? 1 : 0;
}

__global__ void k_convert(const void* __restrict__ in, u16* __restrict__ out,
                          int n, const int* __restrict__ flag) {
    int i = blockIdx.x * blockDim.x + threadIdx.x;
    if (i >= n) return;
    if (*flag) out[i] = f2bf(((const float*)in)[i]);
    else       out[i] = ((const u16*)in)[i];
}

// ---- CSR build ------------------------------------------------------------

__global__ void k_degree(const int* __restrict__ dst, int* __restrict__ cnt, int E) {
    int e = blockIdx.x * blockDim.x + threadIdx.x;
    if (e < E) atomicAdd(&cnt[dst[e]], 1);
}

__global__ void k_scan_blocks(const int* __restrict__ cnt, int* __restrict__ rowp,
                              int* __restrict__ sums, int n) {
    __shared__ int s[256];
    int t = threadIdx.x;
    int i = blockIdx.x * 256 + t;
    int v = (i < n) ? cnt[i] : 0;
    s[t] = v;
    __syncthreads();
    for (int off = 1; off < 256; off <<= 1) {
        int add = (t >= off) ? s[t - off] : 0;
        __syncthreads();
        s[t] += add;
        __syncthreads();
    }
    if (i < n) rowp[i] = s[t] - v;
    if (t == 255) sums[blockIdx.x] = s[255];
}

__global__ void k_scan_top(int* __restrict__ sums, int nb) {
    __shared__ int s[256];
    int t = threadIdx.x;
    int v = (t < nb) ? sums[t] : 0;
    s[t] = v;
    __syncthreads();
    for (int off = 1; off < 256; off <<= 1) {
        int add = (t >= off) ? s[t - off] : 0;
        __syncthreads();
        s[t] += add;
        __syncthreads();
    }
    sums[t] = s[t] - v;
}

__global__ void k_finalize(int* __restrict__ rowp, const int* __restrict__ sums,
                           const int* __restrict__ cnt, float* __restrict__ dinv,
                           int n, int E) {
    int i = blockIdx.x * 256 + threadIdx.x;
    if (i < n) {
        rowp[i] += sums[i >> 8];
        dinv[i] = rsqrtf((float)cnt[i] + 1.0f);   // deg includes self-loop
    }
    if (i == 0) rowp[n] = E;
}

__global__ void k_fill(const int* __restrict__ src, const int* __restrict__ dst,
                       const int* __restrict__ rowp, int* __restrict__ fill,
                       int* __restrict__ col, int E) {
    int e = blockIdx.x * blockDim.x + threadIdx.x;
    if (e < E) {
        int d = dst[e];
        int p = rowp[d] + atomicAdd(&fill[d], 1);
        col[p] = src[e];
    }
}

// ---- GEMM (bf16 MFMA) with fused dinv scaling: out = (A @ W) * dinv[:,None]

template <int NOUT>
__global__ void k_gemm_scale(const u16* __restrict__ A, const u16* __restrict__ W,
                             const float* __restrict__ dinv, u16* __restrict__ out, int M) {
    __shared__ u16 Wt[NOUT][136];
    int t = threadIdx.x;
    for (int idx = t; idx < NOUT * 128; idx += 256) {
        int k = idx / NOUT, n = idx % NOUT;   // W row-major [128][NOUT]
        Wt[n][k] = W[idx];
    }
    __syncthreads();
    int wave = t >> 6, lane = t & 63;
    int m0 = (blockIdx.x * 4 + wave) * 16;
    if (m0 >= M) return;
    int q = lane >> 4;
    int mr = lane & 15;

    const u16* arow = A + (size_t)(m0 + mr) * 128 + q * 8;
    short8 a[4];
#pragma unroll
    for (int c = 0; c < 4; c++) a[c] = *(const short8*)(arow + c * 32);

    f32x4 acc[NOUT / 16];
#pragma unroll
    for (int tl = 0; tl < NOUT / 16; tl++) acc[tl] = (f32x4){0.f, 0.f, 0.f, 0.f};

#pragma unroll
    for (int c = 0; c < 4; c++) {
#pragma unroll
        for (int tl = 0; tl < NOUT / 16; tl++) {
            short8 b = *(const short8*)(&Wt[tl * 16 + mr][c * 32 + q * 8]);
            acc[tl] = __builtin_amdgcn_mfma_f32_16x16x32_bf16(a[c], b, acc[tl], 0, 0, 0);
        }
    }

    int rbase = m0 + q * 4;   // C/D: col=lane&15, row=(lane>>4)*4+reg
#pragma unroll
    for (int tl = 0; tl < NOUT / 16; tl++) {
#pragma unroll
        for (int r = 0; r < 4; r++) {
            int row = rbase + r;
            float v = acc[tl][r] * dinv[row];
            out[(size_t)row * NOUT + tl * 16 + mr] = f2bf(v);
        }
    }
}

// ---- CSR gather aggregation -----------------------------------------------
// One block per dst node, F threads (thread = feature). Neighbor indices are
// staged in LDS (coalesced col read, then uniform-address LDS broadcast), and
// the edge loop is unrolled x4 into independent accumulators so 4 gather
// loads are in flight instead of a serial col->g->add chain per edge.

template <int F>
__global__ void k_aggregate(const u16* __restrict__ g, const int* __restrict__ rowp,
                            const int* __restrict__ col, const float* __restrict__ dinv,
                            const u16* __restrict__ bias, u16* __restrict__ outh,
                            float* __restrict__ outf, const int* __restrict__ flag,
                            int N, int E) {
    __shared__ int cs[512];
    int d = blockIdx.x;
    int f = threadIdx.x;
    int beg = rowp[d], end = rowp[d + 1];
    if (beg < 0) beg = 0;
    if (end > E) end = E;
    int deg = end - beg;

    float acc0 = 0.f, acc1 = 0.f, acc2 = 0.f, acc3 = 0.f;
    for (int base = 0; base < deg; base += 512) {
        int cnt = deg - base; if (cnt > 512) cnt = 512;
        __syncthreads();
        for (int i = f; i < cnt; i += F) {
            int s = col[beg + base + i];
            cs[i] = s < 0 ? 0 : (s >= N ? N - 1 : s);   // defensive clamp
        }
        __syncthreads();
        int e = 0;
        for (; e + 4 <= cnt; e += 4) {
            int s0 = cs[e], s1 = cs[e + 1], s2 = cs[e + 2], s3 = cs[e + 3];
            acc0 += bf2f(g[(size_t)s0 * F + f]);
            acc1 += bf2f(g[(size_t)s1 * F + f]);
            acc2 += bf2f(g[(size_t)s2 * F + f]);
            acc3 += bf2f(g[(size_t)s3 * F + f]);
        }
        int r = cnt - e;
        if (r > 0) acc0 += bf2f(g[(size_t)cs[e] * F + f]);
        if (r > 1) acc1 += bf2f(g[(size_t)cs[e + 1] * F + f]);
        if (r > 2) acc2 += bf2f(g[(size_t)cs[e + 2] * F + f]);
    }
    float acc = (acc0 + acc1) + (acc2 + acc3);
    float v = dinv[d] * (acc + bf2f(g[(size_t)d * F + f])) + bf2f(bias[f]);
    v = v > 0.f ? v : 0.f;
    size_t o = (size_t)d * F + f;
    if (flag && *flag) outf[o] = v;
    else               outh[o] = f2bf(v);
}

// ---- launch ---------------------------------------------------------------

extern "C" void kernel_launch(void* const* d_in, const int* in_sizes, int n_in,
                              void* d_out, int out_size, void* d_ws, size_t ws_size,
                              hipStream_t stream) {
    const int N = in_sizes[0] / 128;
    const int E = in_sizes[1] / 2;
    const int* ei = (const int*)d_in[1];
    const int* src = ei;
    const int* dst = ei + E;

    char* p = (char*)d_ws;
    auto alloc = [&](size_t b) { char* r = p; p += (b + 255) & ~(size_t)255; return r; };
    int*   flag = (int*)alloc(256);
    int*   rowp = (int*)alloc((size_t)(N + 1) * 4);
    float* dinv = (float*)alloc((size_t)N * 4);
    int*   col  = (int*)alloc((size_t)E * 4);
    u16*   wbuf = (u16*)alloc((size_t)(128 * 128 + 128 + 128 * 64 + 64) * 2);
    char*  slotA = alloc((size_t)N * 128 * 2);   // cnt/fill/sums early; g1; g2
    char*  slotB = alloc((size_t)N * 128 * 2);   // xC early; o1 later

    int* cnt  = (int*)slotA;
    int* fill = (int*)(slotA + (size_t)N * 4);
    int* sums = (int*)(slotA + (size_t)2 * N * 4);
    u16* g1   = (u16*)slotA;
    u16* g2   = (u16*)slotA;
    u16* xC   = (u16*)slotB;
    u16* o1   = (u16*)slotB;
    u16* W1C = wbuf;
    u16* b1C = wbuf + 128 * 128;
    u16* W2C = b1C + 128;
    u16* b2C = W2C + 128 * 64;

    // 1. dtype detect + canonicalize to bf16
    k_detect<<<1, 256, 0, stream>>>((const u16*)d_in[0], flag);
    int xel = N * 128;
    k_convert<<<(xel + 255) / 256, 256, 0, stream>>>(d_in[0], xC, xel, flag);
    k_convert<<<64, 256, 0, stream>>>(d_in[2], W1C, 128 * 128, flag);
    k_convert<<<1, 256, 0, stream>>>(d_in[3], b1C, 128, flag);
    k_convert<<<32, 256, 0, stream>>>(d_in[4], W2C, 128 * 64, flag);
    k_convert<<<1, 256, 0, stream>>>(d_in[5], b2C, 64, flag);

    // 2. CSR build
    hipMemsetAsync(slotA, 0, (size_t)2 * N * 4 + 1024, stream);
    int eb = (E + 255) / 256;
    int nb = (N + 255) / 256;
    k_degree<<<eb, 256, 0, stream>>>(dst, cnt, E);
    k_scan_blocks<<<nb, 256, 0, stream>>>(cnt, rowp, sums, N);
    k_scan_top<<<1, 256, 0, stream>>>(sums, nb);
    k_finalize<<<nb, 256, 0, stream>>>(rowp, sums, cnt, dinv, N, E);
    k_fill<<<eb, 256, 0, stream>>>(src, dst, rowp, fill, col, E);

    // 3. layer 1: GEMM (xC @ W1)*dinv -> g1 (slotA), aggregate -> o1 (slotB)
    int gb = (N / 16 + 3) / 4;
    k_gemm_scale<128><<<gb, 256, 0, stream>>>(xC, W1C, dinv, g1, N);
    k_aggregate<128><<<N, 128, 0, stream>>>(g1, rowp, col, dinv, b1C,
                                            o1, nullptr, nullptr, N, E);
    // 4. layer 2: GEMM (o1 @ W2)*dinv -> g2 (slotA), aggregate -> d_out
    k_gemm_scale<64><<<gb, 256, 0, stream>>>(o1, W2C, dinv, g2, N);
    k_aggregate<64><<<N, 64, 0, stream>>>(g2, rowp, col, dinv, b2C,
                                          (u16*)d_out, (float*)d_out, flag, N, E);
}

// Round 5
// 260.185 us; speedup vs baseline: 1.2969x; 1.0552x over previous
//
#include <hip/hip_runtime.h>

typedef unsigned short u16;
typedef __attribute__((ext_vector_type(8))) short short8;
typedef __attribute__((ext_vector_type(4))) float f32x4;

__device__ __forceinline__ float bf2f(u16 h) {
    union { unsigned u; float f; } v; v.u = ((unsigned)h) << 16; return v.f;
}
__device__ __forceinline__ float bflo(unsigned u) {
    union { unsigned u; float f; } v; v.u = u << 16; return v.f;
}
__device__ __forceinline__ float bfhi(unsigned u) {
    union { unsigned u; float f; } v; v.u = u & 0xFFFF0000u; return v.f;
}
__device__ __forceinline__ u16 f2bf(float f) {
    union { float f; unsigned u; } v; v.f = f;
    unsigned u = v.u;
    u += 0x7FFFu + ((u >> 16) & 1u);   // round-to-nearest-even
    return (u16)(u >> 16);
}

// ---- dtype detection ------------------------------------------------------
__global__ void k_detect(const u16* __restrict__ x, int* __restrict__ flag) {
    __shared__ int c_s;
    if (threadIdx.x == 0) c_s = 0;
    __syncthreads();
    int c = 0;
    for (int i = threadIdx.x; i < 2048; i += blockDim.x) {
        int e = (x[2 * i] >> 7) & 0xFF;
        c += (e >= 160 || e <= 80) ? 1 : 0;
    }
    atomicAdd(&c_s, c);
    __syncthreads();
    if (threadIdx.x == 0) *flag = (c_s > 64) ? 1 : 0;
}

__global__ void k_convert(const void* __restrict__ in, u16* __restrict__ out,
                          int n, const int* __restrict__ flag) {
    int i = blockIdx.x * blockDim.x + threadIdx.x;
    if (i >= n) return;
    if (*flag) out[i] = f2bf(((const float*)in)[i]);
    else       out[i] = ((const u16*)in)[i];
}

// all four weight/bias arrays canonicalized to bf16 in one launch
__global__ void k_convert_w(const void* __restrict__ W1, const void* __restrict__ b1,
                            const void* __restrict__ W2, const void* __restrict__ b2,
                            u16* __restrict__ out, const int* __restrict__ flag) {
    const int n1 = 128 * 128, n2 = n1 + 128, n3 = n2 + 128 * 64, n4 = n3 + 64;
    int i = blockIdx.x * 256 + threadIdx.x;
    if (i >= n4) return;
    const void* src; int off;
    if (i < n1)      { src = W1; off = i; }
    else if (i < n2) { src = b1; off = i - n1; }
    else if (i < n3) { src = W2; off = i - n2; }
    else             { src = b2; off = i - n3; }
    out[i] = *flag ? f2bf(((const float*)src)[off]) : ((const u16*)src)[off];
}

// ---- CSR build ------------------------------------------------------------

__global__ void k_degree(const int* __restrict__ dst, int* __restrict__ cnt, int E) {
    int e = blockIdx.x * blockDim.x + threadIdx.x;
    if (e < E) atomicAdd(&cnt[dst[e]], 1);
}

__global__ void k_scan_blocks(const int* __restrict__ cnt, int* __restrict__ rowp,
                              int* __restrict__ sums, int n) {
    __shared__ int s[256];
    int t = threadIdx.x;
    int i = blockIdx.x * 256 + t;
    int v = (i < n) ? cnt[i] : 0;
    s[t] = v;
    __syncthreads();
    for (int off = 1; off < 256; off <<= 1) {
        int add = (t >= off) ? s[t - off] : 0;
        __syncthreads();
        s[t] += add;
        __syncthreads();
    }
    if (i < n) rowp[i] = s[t] - v;
    if (t == 255) sums[blockIdx.x] = s[255];
}

__global__ void k_scan_top(int* __restrict__ sums, int nb) {
    __shared__ int s[256];
    int t = threadIdx.x;
    int v = (t < nb) ? sums[t] : 0;
    s[t] = v;
    __syncthreads();
    for (int off = 1; off < 256; off <<= 1) {
        int add = (t >= off) ? s[t - off] : 0;
        __syncthreads();
        s[t] += add;
        __syncthreads();
    }
    sums[t] = s[t] - v;
}

__global__ void k_finalize(int* __restrict__ rowp, const int* __restrict__ sums,
                           const int* __restrict__ cnt, float* __restrict__ dinv,
                           int n, int E) {
    int i = blockIdx.x * 256 + threadIdx.x;
    if (i < n) {
        rowp[i] += sums[i >> 8];
        dinv[i] = rsqrtf((float)cnt[i] + 1.0f);   // deg includes self-loop
    }
    if (i == 0) rowp[n] = E;
}

__global__ void k_fill(const int* __restrict__ src, const int* __restrict__ dst,
                       const int* __restrict__ rowp, int* __restrict__ fill,
                       int* __restrict__ col, int E) {
    int e = blockIdx.x * blockDim.x + threadIdx.x;
    if (e < E) {
        int d = dst[e];
        int p = rowp[d] + atomicAdd(&fill[d], 1);
        col[p] = src[e];
    }
}

// ---- GEMM (bf16 MFMA) with fused dinv scaling: out = (A @ W) * dinv[:,None]

template <int NOUT>
__global__ void k_gemm_scale(const u16* __restrict__ A, const u16* __restrict__ W,
                             const float* __restrict__ dinv, u16* __restrict__ out, int M) {
    __shared__ u16 Wt[NOUT][136];
    int t = threadIdx.x;
    for (int idx = t; idx < NOUT * 128; idx += 256) {
        int k = idx / NOUT, n = idx % NOUT;   // W row-major [128][NOUT]
        Wt[n][k] = W[idx];
    }
    __syncthreads();
    int wave = t >> 6, lane = t & 63;
    int m0 = (blockIdx.x * 4 + wave) * 16;
    if (m0 >= M) return;
    int q = lane >> 4;
    int mr = lane & 15;

    const u16* arow = A + (size_t)(m0 + mr) * 128 + q * 8;
    short8 a[4];
#pragma unroll
    for (int c = 0; c < 4; c++) a[c] = *(const short8*)(arow + c * 32);

    f32x4 acc[NOUT / 16];
#pragma unroll
    for (int tl = 0; tl < NOUT / 16; tl++) acc[tl] = (f32x4){0.f, 0.f, 0.f, 0.f};

#pragma unroll
    for (int c = 0; c < 4; c++) {
#pragma unroll
        for (int tl = 0; tl < NOUT / 16; tl++) {
            short8 b = *(const short8*)(&Wt[tl * 16 + mr][c * 32 + q * 8]);
            acc[tl] = __builtin_amdgcn_mfma_f32_16x16x32_bf16(a[c], b, acc[tl], 0, 0, 0);
        }
    }

    int rbase = m0 + q * 4;   // C/D: col=lane&15, row=(lane>>4)*4+reg
#pragma unroll
    for (int tl = 0; tl < NOUT / 16; tl++) {
#pragma unroll
        for (int r = 0; r < 4; r++) {
            int row = rbase + r;
            float v = acc[tl][r] * dinv[row];
            out[(size_t)row * NOUT + tl * 16 + mr] = f2bf(v);
        }
    }
}

// ---- CSR gather aggregation -----------------------------------------------
// One WAVE per dst node; control flow is wave-uniform (deg is uniform across
// the wave), lanes differ only in data, so __shfl is always well-defined.
// Lane layout: er = lane/LPR selects edge-in-group, fo = (lane%LPR)*8 selects
// 8 bf16 features loaded as one uint4 (16B). A wave processes EPW edges per
// load instruction, unrolled x2 (2*EPW edges / 2-4KB in flight).

template <int F>
__global__ void k_agg(const u16* __restrict__ g, const int* __restrict__ rowp,
                      const int* __restrict__ col, const float* __restrict__ dinv,
                      const u16* __restrict__ bias, u16* __restrict__ outh,
                      float* __restrict__ outf, const int* __restrict__ flag,
                      int N, int E) {
    constexpr int LPR = F / 8;      // lanes covering one feature row
    constexpr int EPW = 64 / LPR;   // edges per wave load-instruction
    int d = blockIdx.x * 4 + (threadIdx.x >> 6);
    if (d >= N) return;             // wave-uniform exit
    int lane = threadIdx.x & 63;
    int er = lane / LPR;
    int fo = (lane % LPR) * 8;

    int beg = rowp[d], end = rowp[d + 1];
    if (beg < 0) beg = 0;
    if (end > E) end = E;
    int deg = end - beg;

    float a0[8], a1[8];
#pragma unroll
    for (int j = 0; j < 8; j++) { a0[j] = 0.f; a1[j] = 0.f; }

    for (int base = 0; base < deg; base += 64) {   // uniform: deg same for all lanes
        int cnt = deg - base; if (cnt > 64) cnt = 64;
        int colv = 0;
        if (lane < cnt) {                          // predicated load only
            int s = col[beg + base + lane];
            colv = s < 0 ? 0 : (s >= N ? N - 1 : s);
        }
        int full = cnt / EPW;                      // uniform trip count
        int i = 0;
        for (; i + 2 <= full; i += 2) {
            int s0 = __shfl(colv, i * EPW + er, 64);
            int s1 = __shfl(colv, (i + 1) * EPW + er, 64);
            uint4 v0 = *(const uint4*)(g + (size_t)s0 * F + fo);
            uint4 v1 = *(const uint4*)(g + (size_t)s1 * F + fo);
            a0[0] += bflo(v0.x); a0[1] += bfhi(v0.x);
            a0[2] += bflo(v0.y); a0[3] += bfhi(v0.y);
            a0[4] += bflo(v0.z); a0[5] += bfhi(v0.z);
            a0[6] += bflo(v0.w); a0[7] += bfhi(v0.w);
            a1[0] += bflo(v1.x); a1[1] += bfhi(v1.x);
            a1[2] += bflo(v1.y); a1[3] += bfhi(v1.y);
            a1[4] += bflo(v1.z); a1[5] += bfhi(v1.z);
            a1[6] += bflo(v1.w); a1[7] += bfhi(v1.w);
        }
        if (i < full) {
            int s0 = __shfl(colv, i * EPW + er, 64);
            uint4 v0 = *(const uint4*)(g + (size_t)s0 * F + fo);
            a0[0] += bflo(v0.x); a0[1] += bfhi(v0.x);
            a0[2] += bflo(v0.y); a0[3] += bfhi(v0.y);
            a0[4] += bflo(v0.z); a0[5] += bfhi(v0.z);
            a0[6] += bflo(v0.w); a0[7] += bfhi(v0.w);
            i++;
        }
        int rem = cnt - full * EPW;                // 0..EPW-1 leftover edges
        int s0 = __shfl(colv, (full * EPW + er) & 63, 64);   // uniform shfl
        if (er < rem) {                            // predicated load only
            uint4 v0 = *(const uint4*)(g + (size_t)s0 * F + fo);
            a0[0] += bflo(v0.x); a0[1] += bfhi(v0.x);
            a0[2] += bflo(v0.y); a0[3] += bfhi(v0.y);
            a0[4] += bflo(v0.z); a0[5] += bfhi(v0.z);
            a0[6] += bflo(v0.w); a0[7] += bfhi(v0.w);
        }
    }
#pragma unroll
    for (int j = 0; j < 8; j++) a0[j] += a1[j];
    // butterfly: sum across edge groups (all 64 lanes active, uniform)
#pragma unroll
    for (int off = LPR; off < 64; off <<= 1) {
#pragma unroll
        for (int j = 0; j < 8; j++) a0[j] += __shfl_xor(a0[j], off, 64);
    }

    if (lane < LPR) {   // er == 0 lanes own the result
        uint4 sv = *(const uint4*)(g + (size_t)d * F + fo);
        uint4 bv = *(const uint4*)(bias + fo);
        float di = dinv[d];
        float r[8];
        r[0] = di * (a0[0] + bflo(sv.x)) + bflo(bv.x);
        r[1] = di * (a0[1] + bfhi(sv.x)) + bfhi(bv.x);
        r[2] = di * (a0[2] + bflo(sv.y)) + bflo(bv.y);
        r[3] = di * (a0[3] + bfhi(sv.y)) + bfhi(bv.y);
        r[4] = di * (a0[4] + bflo(sv.z)) + bflo(bv.z);
        r[5] = di * (a0[5] + bfhi(sv.z)) + bfhi(bv.z);
        r[6] = di * (a0[6] + bflo(sv.w)) + bflo(bv.w);
        r[7] = di * (a0[7] + bfhi(sv.w)) + bfhi(bv.w);
#pragma unroll
        for (int j = 0; j < 8; j++) r[j] = r[j] > 0.f ? r[j] : 0.f;
        size_t o = (size_t)d * F + fo;
        if (flag && *flag) {
            f32x4 w0 = {r[0], r[1], r[2], r[3]};
            f32x4 w1 = {r[4], r[5], r[6], r[7]};
            *(f32x4*)(outf + o) = w0;
            *(f32x4*)(outf + o + 4) = w1;
        } else {
            uint4 w;
            w.x = (unsigned)f2bf(r[0]) | ((unsigned)f2bf(r[1]) << 16);
            w.y = (unsigned)f2bf(r[2]) | ((unsigned)f2bf(r[3]) << 16);
            w.z = (unsigned)f2bf(r[4]) | ((unsigned)f2bf(r[5]) << 16);
            w.w = (unsigned)f2bf(r[6]) | ((unsigned)f2bf(r[7]) << 16);
            *(uint4*)(outh + o) = w;
        }
    }
}

// ---- launch ---------------------------------------------------------------

extern "C" void kernel_launch(void* const* d_in, const int* in_sizes, int n_in,
                              void* d_out, int out_size, void* d_ws, size_t ws_size,
                              hipStream_t stream) {
    const int N = in_sizes[0] / 128;
    const int E = in_sizes[1] / 2;
    const int* ei = (const int*)d_in[1];
    const int* src = ei;
    const int* dst = ei + E;

    char* p = (char*)d_ws;
    auto alloc = [&](size_t b) { char* r = p; p += (b + 255) & ~(size_t)255; return r; };
    int*   flag = (int*)alloc(256);
    int*   rowp = (int*)alloc((size_t)(N + 1) * 4);
    float* dinv = (float*)alloc((size_t)N * 4);
    int*   col  = (int*)alloc((size_t)E * 4);
    u16*   wbuf = (u16*)alloc((size_t)(128 * 128 + 128 + 128 * 64 + 64) * 2);
    char*  slotA = alloc((size_t)N * 128 * 2);   // cnt/fill/sums early; g1; g2
    char*  slotB = alloc((size_t)N * 128 * 2);   // xC early; o1 later

    int* cnt  = (int*)slotA;
    int* fill = (int*)(slotA + (size_t)N * 4);
    int* sums = (int*)(slotA + (size_t)2 * N * 4);
    u16* g1   = (u16*)slotA;
    u16* g2   = (u16*)slotA;
    u16* xC   = (u16*)slotB;
    u16* o1   = (u16*)slotB;
    u16* W1C = wbuf;
    u16* b1C = wbuf + 128 * 128;
    u16* W2C = b1C + 128;
    u16* b2C = W2C + 128 * 64;

    // 1. dtype detect + canonicalize to bf16
    k_detect<<<1, 256, 0, stream>>>((const u16*)d_in[0], flag);
    int xel = N * 128;
    k_convert<<<(xel + 255) / 256, 256, 0, stream>>>(d_in[0], xC, xel, flag);
    k_convert_w<<<97, 256, 0, stream>>>(d_in[2], d_in[3], d_in[4], d_in[5], wbuf, flag);

    // 2. CSR build
    hipMemsetAsync(slotA, 0, (size_t)2 * N * 4 + 1024, stream);
    int eb = (E + 255) / 256;
    int nb = (N + 255) / 256;
    k_degree<<<eb, 256, 0, stream>>>(dst, cnt, E);
    k_scan_blocks<<<nb, 256, 0, stream>>>(cnt, rowp, sums, N);
    k_scan_top<<<1, 256, 0, stream>>>(sums, nb);
    k_finalize<<<nb, 256, 0, stream>>>(rowp, sums, cnt, dinv, N, E);
    k_fill<<<eb, 256, 0, stream>>>(src, dst, rowp, fill, col, E);

    // 3. layer 1: GEMM (xC @ W1)*dinv -> g1 (slotA), aggregate -> o1 (slotB)
    int gb = (N / 16 + 3) / 4;
    int ab = (N + 3) / 4;   // one wave per node, 4 waves/block
    k_gemm_scale<128><<<gb, 256, 0, stream>>>(xC, W1C, dinv, g1, N);
    k_agg<128><<<ab, 256, 0, stream>>>(g1, rowp, col, dinv, b1C,
                                       o1, nullptr, nullptr, N, E);
    // 4. layer 2: GEMM (o1 @ W2)*dinv -> g2 (slotA), aggregate -> d_out
    k_gemm_scale<64><<<gb, 256, 0, stream>>>(o1, W2C, dinv, g2, N);
    k_agg<64><<<ab, 256, 0, stream>>>(g2, rowp, col, dinv, b2C,
                                      (u16*)d_out, (float*)d_out, flag, N, E);
}

// Round 6
// 218.676 us; speedup vs baseline: 1.5430x; 1.1898x over previous
//
#include <hip/hip_runtime.h>

typedef unsigned short u16;
typedef __attribute__((ext_vector_type(8))) short short8;
typedef __attribute__((ext_vector_type(4))) float f32x4;

__device__ __forceinline__ float bf2f(u16 h) {
    union { unsigned u; float f; } v; v.u = ((unsigned)h) << 16; return v.f;
}
__device__ __forceinline__ float bflo(unsigned u) {
    union { unsigned u; float f; } v; v.u = u << 16; return v.f;
}
__device__ __forceinline__ float bfhi(unsigned u) {
    union { unsigned u; float f; } v; v.u = u & 0xFFFF0000u; return v.f;
}
__device__ __forceinline__ u16 f2bf(float f) {
    union { float f; unsigned u; } v; v.f = f;
    unsigned u = v.u;
    u += 0x7FFFu + ((u >> 16) & 1u);   // round-to-nearest-even
    return (u16)(u >> 16);
}

// ---- dtype detection (insurance; measured runs are bf16 => flag=0) --------
__global__ void k_detect(const u16* __restrict__ x, int* __restrict__ flag) {
    __shared__ int c_s;
    if (threadIdx.x == 0) c_s = 0;
    __syncthreads();
    int c = 0;
    for (int i = threadIdx.x; i < 2048; i += blockDim.x) {
        int e = (x[2 * i] >> 7) & 0xFF;
        c += (e >= 160 || e <= 80) ? 1 : 0;
    }
    atomicAdd(&c_s, c);
    __syncthreads();
    if (threadIdx.x == 0) *flag = (c_s > 64) ? 1 : 0;
}

// all four weight/bias arrays canonicalized to bf16 in one launch
__global__ void k_convert_w(const void* __restrict__ W1, const void* __restrict__ b1,
                            const void* __restrict__ W2, const void* __restrict__ b2,
                            u16* __restrict__ out, const int* __restrict__ flag) {
    const int n1 = 128 * 128, n2 = n1 + 128, n3 = n2 + 128 * 64, n4 = n3 + 64;
    int i = blockIdx.x * 256 + threadIdx.x;
    if (i >= n4) return;
    const void* src; int off;
    if (i < n1)      { src = W1; off = i; }
    else if (i < n2) { src = b1; off = i - n1; }
    else if (i < n3) { src = W2; off = i - n2; }
    else             { src = b2; off = i - n3; }
    out[i] = *flag ? f2bf(((const float*)src)[off]) : ((const u16*)src)[off];
}

// ---- CSR build ------------------------------------------------------------
// Pass 1: degree histogram AND per-edge slot in one atomic (halves total
// atomics vs separate degree+fill; the fill pass then needs no atomic chain).

__global__ void k_degpos(const int* __restrict__ dst, int* __restrict__ cnt,
                         int* __restrict__ pos, int E) {
    int e = blockIdx.x * blockDim.x + threadIdx.x;
    if (e < E) pos[e] = atomicAdd(&cnt[dst[e]], 1);
}

__global__ void k_scan_blocks(const int* __restrict__ cnt, int* __restrict__ rowp,
                              int* __restrict__ sums, int n) {
    __shared__ int s[256];
    int t = threadIdx.x;
    int i = blockIdx.x * 256 + t;
    int v = (i < n) ? cnt[i] : 0;
    s[t] = v;
    __syncthreads();
    for (int off = 1; off < 256; off <<= 1) {
        int add = (t >= off) ? s[t - off] : 0;
        __syncthreads();
        s[t] += add;
        __syncthreads();
    }
    if (i < n) rowp[i] = s[t] - v;
    if (t == 255) sums[blockIdx.x] = s[255];
}

__global__ void k_scan_top(int* __restrict__ sums, int nb) {
    __shared__ int s[256];
    int t = threadIdx.x;
    int v = (t < nb) ? sums[t] : 0;
    s[t] = v;
    __syncthreads();
    for (int off = 1; off < 256; off <<= 1) {
        int add = (t >= off) ? s[t - off] : 0;
        __syncthreads();
        s[t] += add;
        __syncthreads();
    }
    sums[t] = s[t] - v;
}

__global__ void k_finalize(int* __restrict__ rowp, const int* __restrict__ sums,
                           const int* __restrict__ cnt, float* __restrict__ dinv,
                           int n, int E) {
    int i = blockIdx.x * 256 + threadIdx.x;
    if (i < n) {
        rowp[i] += sums[i >> 8];
        dinv[i] = rsqrtf((float)cnt[i] + 1.0f);   // deg includes self-loop
    }
    if (i == 0) rowp[n] = E;
}

// Pass 2: atomic-free scatter (position precomputed in pass 1).
__global__ void k_fill2(const int* __restrict__ src, const int* __restrict__ dst,
                        const int* __restrict__ pos, const int* __restrict__ rowp,
                        int* __restrict__ col, int E) {
    int e = blockIdx.x * blockDim.x + threadIdx.x;
    if (e < E) col[rowp[dst[e]] + pos[e]] = src[e];
}

// ---- GEMM (bf16 MFMA), fused dinv scale; A read as f32 or bf16 per flag ---
// flag==nullptr => A is bf16 unconditionally (used for layer 2: o1 is bf16).

template <int NOUT>
__global__ void k_gemm_scale(const void* __restrict__ Av, const u16* __restrict__ W,
                             const float* __restrict__ dinv, u16* __restrict__ out,
                             int M, const int* __restrict__ flag) {
    __shared__ u16 Wt[NOUT][136];
    int t = threadIdx.x;
    for (int idx = t; idx < NOUT * 128; idx += 256) {
        int k = idx / NOUT, n = idx % NOUT;   // W row-major [128][NOUT]
        Wt[n][k] = W[idx];
    }
    __syncthreads();
    int wave = t >> 6, lane = t & 63;
    int m0 = (blockIdx.x * 4 + wave) * 16;
    if (m0 >= M) return;
    int q = lane >> 4;
    int mr = lane & 15;

    short8 a[4];
    if (flag && *flag) {
        const float* arow = (const float*)Av + (size_t)(m0 + mr) * 128 + q * 8;
#pragma unroll
        for (int c = 0; c < 4; c++) {
            f32x4 lo = *(const f32x4*)(arow + c * 32);
            f32x4 hi = *(const f32x4*)(arow + c * 32 + 4);
            a[c][0] = (short)f2bf(lo.x); a[c][1] = (short)f2bf(lo.y);
            a[c][2] = (short)f2bf(lo.z); a[c][3] = (short)f2bf(lo.w);
            a[c][4] = (short)f2bf(hi.x); a[c][5] = (short)f2bf(hi.y);
            a[c][6] = (short)f2bf(hi.z); a[c][7] = (short)f2bf(hi.w);
        }
    } else {
        const u16* arow = (const u16*)Av + (size_t)(m0 + mr) * 128 + q * 8;
#pragma unroll
        for (int c = 0; c < 4; c++) a[c] = *(const short8*)(arow + c * 32);
    }

    f32x4 acc[NOUT / 16];
#pragma unroll
    for (int tl = 0; tl < NOUT / 16; tl++) acc[tl] = (f32x4){0.f, 0.f, 0.f, 0.f};

#pragma unroll
    for (int c = 0; c < 4; c++) {
#pragma unroll
        for (int tl = 0; tl < NOUT / 16; tl++) {
            short8 b = *(const short8*)(&Wt[tl * 16 + mr][c * 32 + q * 8]);
            acc[tl] = __builtin_amdgcn_mfma_f32_16x16x32_bf16(a[c], b, acc[tl], 0, 0, 0);
        }
    }

    int rbase = m0 + q * 4;   // C/D: col=lane&15, row=(lane>>4)*4+reg
#pragma unroll
    for (int tl = 0; tl < NOUT / 16; tl++) {
#pragma unroll
        for (int r = 0; r < 4; r++) {
            int row = rbase + r;
            float v = acc[tl][r] * dinv[row];
            out[(size_t)row * NOUT + tl * 16 + mr] = f2bf(v);
        }
    }
}

// ---- CSR gather aggregation (round-5 passing version, unchanged) ----------

template <int F>
__global__ void k_agg(const u16* __restrict__ g, const int* __restrict__ rowp,
                      const int* __restrict__ col, const float* __restrict__ dinv,
                      const u16* __restrict__ bias, u16* __restrict__ outh,
                      float* __restrict__ outf, const int* __restrict__ flag,
                      int N, int E) {
    constexpr int LPR = F / 8;      // lanes covering one feature row
    constexpr int EPW = 64 / LPR;   // edges per wave load-instruction
    int d = blockIdx.x * 4 + (threadIdx.x >> 6);
    if (d >= N) return;             // wave-uniform exit
    int lane = threadIdx.x & 63;
    int er = lane / LPR;
    int fo = (lane % LPR) * 8;

    int beg = rowp[d], end = rowp[d + 1];
    if (beg < 0) beg = 0;
    if (end > E) end = E;
    int deg = end - beg;

    float a0[8], a1[8];
#pragma unroll
    for (int j = 0; j < 8; j++) { a0[j] = 0.f; a1[j] = 0.f; }

    for (int base = 0; base < deg; base += 64) {   // uniform: deg same for all lanes
        int cnt = deg - base; if (cnt > 64) cnt = 64;
        int colv = 0;
        if (lane < cnt) {                          // predicated load only
            int s = col[beg + base + lane];
            colv = s < 0 ? 0 : (s >= N ? N - 1 : s);
        }
        int full = cnt / EPW;                      // uniform trip count
        int i = 0;
        for (; i + 2 <= full; i += 2) {
            int s0 = __shfl(colv, i * EPW + er, 64);
            int s1 = __shfl(colv, (i + 1) * EPW + er, 64);
            uint4 v0 = *(const uint4*)(g + (size_t)s0 * F + fo);
            uint4 v1 = *(const uint4*)(g + (size_t)s1 * F + fo);
            a0[0] += bflo(v0.x); a0[1] += bfhi(v0.x);
            a0[2] += bflo(v0.y); a0[3] += bfhi(v0.y);
            a0[4] += bflo(v0.z); a0[5] += bfhi(v0.z);
            a0[6] += bflo(v0.w); a0[7] += bfhi(v0.w);
            a1[0] += bflo(v1.x); a1[1] += bfhi(v1.x);
            a1[2] += bflo(v1.y); a1[3] += bfhi(v1.y);
            a1[4] += bflo(v1.z); a1[5] += bfhi(v1.z);
            a1[6] += bflo(v1.w); a1[7] += bfhi(v1.w);
        }
        if (i < full) {
            int s0 = __shfl(colv, i * EPW + er, 64);
            uint4 v0 = *(const uint4*)(g + (size_t)s0 * F + fo);
            a0[0] += bflo(v0.x); a0[1] += bfhi(v0.x);
            a0[2] += bflo(v0.y); a0[3] += bfhi(v0.y);
            a0[4] += bflo(v0.z); a0[5] += bfhi(v0.z);
            a0[6] += bflo(v0.w); a0[7] += bfhi(v0.w);
            i++;
        }
        int rem = cnt - full * EPW;                // 0..EPW-1 leftover edges
        int s0 = __shfl(colv, (full * EPW + er) & 63, 64);   // uniform shfl
        if (er < rem) {                            // predicated load only
            uint4 v0 = *(const uint4*)(g + (size_t)s0 * F + fo);
            a0[0] += bflo(v0.x); a0[1] += bfhi(v0.x);
            a0[2] += bflo(v0.y); a0[3] += bfhi(v0.y);
            a0[4] += bflo(v0.z); a0[5] += bfhi(v0.z);
            a0[6] += bflo(v0.w); a0[7] += bfhi(v0.w);
        }
    }
#pragma unroll
    for (int j = 0; j < 8; j++) a0[j] += a1[j];
    // butterfly: sum across edge groups (all 64 lanes active, uniform)
#pragma unroll
    for (int off = LPR; off < 64; off <<= 1) {
#pragma unroll
        for (int j = 0; j < 8; j++) a0[j] += __shfl_xor(a0[j], off, 64);
    }

    if (lane < LPR) {   // er == 0 lanes own the result
        uint4 sv = *(const uint4*)(g + (size_t)d * F + fo);
        uint4 bv = *(const uint4*)(bias + fo);
        float di = dinv[d];
        float r[8];
        r[0] = di * (a0[0] + bflo(sv.x)) + bflo(bv.x);
        r[1] = di * (a0[1] + bfhi(sv.x)) + bfhi(bv.x);
        r[2] = di * (a0[2] + bflo(sv.y)) + bflo(bv.y);
        r[3] = di * (a0[3] + bfhi(sv.y)) + bfhi(bv.y);
        r[4] = di * (a0[4] + bflo(sv.z)) + bflo(bv.z);
        r[5] = di * (a0[5] + bfhi(sv.z)) + bfhi(bv.z);
        r[6] = di * (a0[6] + bflo(sv.w)) + bflo(bv.w);
        r[7] = di * (a0[7] + bfhi(sv.w)) + bfhi(bv.w);
#pragma unroll
        for (int j = 0; j < 8; j++) r[j] = r[j] > 0.f ? r[j] : 0.f;
        size_t o = (size_t)d * F + fo;
        if (flag && *flag) {
            f32x4 w0 = {r[0], r[1], r[2], r[3]};
            f32x4 w1 = {r[4], r[5], r[6], r[7]};
            *(f32x4*)(outf + o) = w0;
            *(f32x4*)(outf + o + 4) = w1;
        } else {
            uint4 w;
            w.x = (unsigned)f2bf(r[0]) | ((unsigned)f2bf(r[1]) << 16);
            w.y = (unsigned)f2bf(r[2]) | ((unsigned)f2bf(r[3]) << 16);
            w.z = (unsigned)f2bf(r[4]) | ((unsigned)f2bf(r[5]) << 16);
            w.w = (unsigned)f2bf(r[6]) | ((unsigned)f2bf(r[7]) << 16);
            *(uint4*)(outh + o) = w;
        }
    }
}

// ---- launch ---------------------------------------------------------------

extern "C" void kernel_launch(void* const* d_in, const int* in_sizes, int n_in,
                              void* d_out, int out_size, void* d_ws, size_t ws_size,
                              hipStream_t stream) {
    const int N = in_sizes[0] / 128;
    const int E = in_sizes[1] / 2;
    const int* ei = (const int*)d_in[1];
    const int* src = ei;
    const int* dst = ei + E;

    char* p = (char*)d_ws;
    auto alloc = [&](size_t b) { char* r = p; p += (b + 255) & ~(size_t)255; return r; };
    int*   flag = (int*)alloc(256);
    int*   rowp = (int*)alloc((size_t)(N + 1) * 4);
    float* dinv = (float*)alloc((size_t)N * 4);
    int*   col  = (int*)alloc((size_t)E * 4);
    u16*   wbuf = (u16*)alloc((size_t)(128 * 128 + 128 + 128 * 64 + 64) * 2);
    char*  slotA = alloc((size_t)N * 128 * 2);   // cnt+sums early; g1; g2
    char*  slotB = alloc((size_t)N * 128 * 2);   // pos early; o1 later

    int* cnt  = (int*)slotA;                     // dead after k_finalize
    int* sums = (int*)(slotA + (size_t)N * 4);   // dead after k_finalize
    u16* g1   = (u16*)slotA;                     // written by gemm1
    u16* g2   = (u16*)slotA;                     // written by gemm2
    int* pos  = (int*)slotB;                     // dead after k_fill2
    u16* o1   = (u16*)slotB;                     // written by agg1
    u16* W1C = wbuf;
    u16* b1C = wbuf + 128 * 128;
    u16* W2C = b1C + 128;
    u16* b2C = W2C + 128 * 64;

    // 1. dtype detect + weight canonicalization
    k_detect<<<1, 256, 0, stream>>>((const u16*)d_in[0], flag);
    k_convert_w<<<97, 256, 0, stream>>>(d_in[2], d_in[3], d_in[4], d_in[5], wbuf, flag);

    // 2. CSR build (single atomic pass)
    hipMemsetAsync(slotA, 0, (size_t)N * 4 + 1024, stream);   // cnt + sums
    int eb = (E + 255) / 256;
    int nb = (N + 255) / 256;
    k_degpos<<<eb, 256, 0, stream>>>(dst, cnt, pos, E);
    k_scan_blocks<<<nb, 256, 0, stream>>>(cnt, rowp, sums, N);
    k_scan_top<<<1, 256, 0, stream>>>(sums, nb);
    k_finalize<<<nb, 256, 0, stream>>>(rowp, sums, cnt, dinv, N, E);
    k_fill2<<<eb, 256, 0, stream>>>(src, dst, pos, rowp, col, E);

    // 3. layer 1: GEMM reads x directly (dual-dtype) -> g1; aggregate -> o1
    int gb = (N / 16 + 3) / 4;
    int ab = (N + 3) / 4;   // one wave per node, 4 waves/block
    k_gemm_scale<128><<<gb, 256, 0, stream>>>(d_in[0], W1C, dinv, g1, N, flag);
    k_agg<128><<<ab, 256, 0, stream>>>(g1, rowp, col, dinv, b1C,
                                       o1, nullptr, nullptr, N, E);
    // 4. layer 2: o1 is always bf16 -> flag=nullptr
    k_gemm_scale<64><<<gb, 256, 0, stream>>>(o1, W2C, dinv, g2, N, nullptr);
    k_agg<64><<<ab, 256, 0, stream>>>(g2, rowp, col, dinv, b2C,
                                      (u16*)d_out, (float*)d_out, flag, N, E);
}